// Round 10
// baseline (168.844 us; speedup 1.0000x reference)
//
#include <hip/hip_runtime.h>
#include <hip/hip_bf16.h>
#include <math.h>

// Problem constants
#define Bb   4
#define Cc   128
#define Nn   4096          // 64*64 spatial
#define BN   (Bb * Nn)
#define HP   0.1f
#define EPSN 1e-10f
#define EPSM 0.001f

typedef __attribute__((ext_vector_type(8))) short short8;  // 8 bf16 = 4 VGPRs
typedef __attribute__((ext_vector_type(4))) float f32x4;   // MFMA accumulator

// Workspace layout (float offsets)
#define OFF_MEAN 0                 // [B*C]     = 512     (atomicAdd -> zeroed)
#define OFF_ACC  512               // [B]       = 4       (atomicAdd -> zeroed)
#define OFF_CTV  1024              // [B*N*2]   = 32768   (fully overwritten)
#define OFF_PMAX 33792             // [64][B*N] = 1048576 (fully overwritten)
#define OFF_SSP  OFF_PMAX          // ssp ALIASES pmax (pmax dead after k_dmin)
#define OFF_FXN  1082368           // bf16 packed [B*N*C] = 1048576 floats
#define OFF_FYN  2130944           // bf16 packed [B*N*C]

// Packed fragment-major layout (per batch, element index):
//   pk(n,k) = (n>>4)*2048 + (k>>3)*128 + (n&15)*8 + (k&7)
// -> an MFMA A/B fragment load (16 rows x 8 ch) is one lane-linear 1 KB
//    global_load_dwordx4 (lane offset = (q*16+l15)*16 B). No gather, no LDS.

__device__ __forceinline__ ushort f2bf(float v)
{
    __hip_bfloat16 h = __float2bfloat16(v);
    return *(ushort*)&h;
}

// ---------------------------------------------------------------------------
// Kernel 1: per-(b,c) sums of feature_y over spatial dim (atomicAdd partials)
__global__ void k_mean(const float* __restrict__ fy, float* __restrict__ mean)
{
    int b = blockIdx.x >> 5;
    int chunk = blockIdx.x & 31;
    int c = threadIdx.x;           // 128 threads, one per channel
    const float* p = fy + ((size_t)b * Nn + (size_t)chunk * 128) * Cc + c;
    float s = 0.f;
    for (int n = 0; n < 128; ++n) s += p[(size_t)n * Cc];
    atomicAdd(&mean[b * Cc + c], s);
}

// ---------------------------------------------------------------------------
// Kernel 2: center by spatial mean of y, L2-normalize over C, emit bf16 in
// PACKED layout. Block = 16 rows; thread t: row r = t>>4, chunk c = t&15.
__global__ void k_norm(const float* __restrict__ fx, const float* __restrict__ fy,
                       const float* __restrict__ mean,
                       ushort* __restrict__ fxn, ushort* __restrict__ fyn)
{
    const int bn0 = blockIdx.x * 16;
    const int b = bn0 >> 12;
    const int t = threadIdx.x;
    const int r = t >> 4, c = t & 15;
    const int row = bn0 + r;

    const float* px = fx + (size_t)row * Cc + c * 8;
    const float* py = fy + (size_t)row * Cc + c * 8;
    const float* pm = mean + b * Cc + c * 8;

    float xv[8], yv[8];
    float sx = 0.f, sy = 0.f;
    #pragma unroll
    for (int e = 0; e < 8; ++e) {
        float m = pm[e] * (1.f / Nn);
        float x = px[e] - m;
        float y = py[e] - m;
        xv[e] = x; yv[e] = y;
        sx += x * x; sy += y * y;
    }
    #pragma unroll
    for (int o = 1; o < 16; o <<= 1) {
        sx += __shfl_xor(sx, o);
        sy += __shfl_xor(sy, o);
    }
    float ix = 1.f / (sqrtf(sx) + EPSN);
    float iy = 1.f / (sqrtf(sy) + EPSN);

    size_t dst = (size_t)b * Nn * Cc
               + (size_t)((bn0 & (Nn - 1)) >> 4) * 2048 + c * 128 + r * 8;
    ushort ox[8], oy[8];
    #pragma unroll
    for (int e = 0; e < 8; ++e) {
        ox[e] = f2bf(xv[e] * ix);
        oy[e] = f2bf(yv[e] * iy);
    }
    *(short8*)&fxn[dst] = *(short8*)ox;
    *(short8*)&fyn[dst] = *(short8*)oy;
}

// ---------------------------------------------------------------------------
// MFMA core: per batch, S = X · Y^T  (M=N=4096, K=C=128).
// ZERO LDS, ZERO BARRIERS. Block (bx,my,b) = 128 n-rows x 4 m-tiles; 4 waves
// in 2x2; wave = 64x64 subtile. A-fragments (af, 64 VGPRs) loaded once and
// carried across the mt loop (the ONLY carried state; acc born+dies per mt
// -> AGPRs, the r2/r7-r9 no-spill rule). All fragment loads are lane-linear
// 1 KB dwordx4 from the packed layout (L2-resident). Each wave folds its 4
// j-tiles + 16 columns and stores its own partial: 64 partials/row, no
// cross-wave combine -> no syncthreads anywhere. The barrier-free mt loop
// lets the compiler hoist mt+1's 16 independent B-loads under mt's MFMAs.
// PASS 1: per-row per-(mt,wx) max of dot -> pmax[z][b*N+row], z=(my*4+mt)*2+wx
// PASS 2: per-row per-(mt,wx) sum exp(fma(dot,c1,c0)) -> ssp[z][...], ctv global.
template <int PASS>
__global__ __launch_bounds__(256, 1) void k_gemm(
    const ushort* __restrict__ fxn, const ushort* __restrict__ fyn,
    float* __restrict__ pmax, const float* __restrict__ ctv,
    float* __restrict__ ssp)
{
    const int tid  = threadIdx.x;
    const int lane = tid & 63;
    const int w    = tid >> 6;
    const int wy = w >> 1, wx = w & 1;
    const int l15 = lane & 15, q = lane >> 4;
    const int n0 = blockIdx.x * 128;
    const int my = blockIdx.y;             // 0..7 -> m-tiles my*4 .. my*4+3
    const int b  = blockIdx.z;

    const ushort* pA = fxn + (size_t)b * Nn * Cc
                     + (size_t)((n0 + wy * 64) >> 4) * 2048 + q * 128 + l15 * 8;
    const ushort* pBb = fyn + (size_t)b * Nn * Cc + q * 128 + l15 * 8;

    // A fragments for the whole block: 16 lane-linear loads, carried in regs.
    short8 af[4][4];
    #pragma unroll
    for (int kt = 0; kt < 4; ++kt)
        #pragma unroll
        for (int i = 0; i < 4; ++i)
            af[kt][i] = *(const short8*)(pA + i * 2048 + kt * 512);

    const float2* ctvp = (PASS == 2)
        ? (const float2*)ctv + (size_t)b * Nn + n0 + wy * 64 : nullptr;

    #pragma unroll 1
    for (int mt = 0; mt < 4; ++mt) {
        const int m0 = (my * 4 + mt) * 128;
        const ushort* pB = pBb + (size_t)((m0 + wx * 64) >> 4) * 2048;

        f32x4 acc[4][4];
        #pragma unroll
        for (int i = 0; i < 4; ++i)
            #pragma unroll
            for (int j = 0; j < 4; ++j)
                acc[i][j] = (f32x4){0.f, 0.f, 0.f, 0.f};

        #pragma unroll
        for (int kt = 0; kt < 4; ++kt) {
            short8 bb[4];
            #pragma unroll
            for (int j = 0; j < 4; ++j)
                bb[j] = *(const short8*)(pB + j * 2048 + kt * 512);
            #pragma unroll
            for (int i = 0; i < 4; ++i)
                #pragma unroll
                for (int j = 0; j < 4; ++j)
                    acc[i][j] = __builtin_amdgcn_mfma_f32_16x16x32_bf16(
                        af[kt][i], bb[j], acc[i][j], 0, 0, 0);
        }

        // Wave-local epilogue. C/D: col = lane&15, row = (lane>>4)*4+reg [m89].
        const int z = (my * 4 + mt) * 2 + wx;
        float* dst = ((PASS == 1) ? pmax : ssp) + (size_t)z * BN + b * Nn
                   + n0 + wy * 64;
        #pragma unroll
        for (int i = 0; i < 4; ++i)
            #pragma unroll
            for (int r = 0; r < 4; ++r) {
                float v;
                if (PASS == 1) {
                    v = fmaxf(fmaxf(acc[i][0][r], acc[i][1][r]),
                              fmaxf(acc[i][2][r], acc[i][3][r]));
                    #pragma unroll
                    for (int o = 1; o < 16; o <<= 1)
                        v = fmaxf(v, __shfl_xor(v, o));
                } else {
                    float2 cc = ctvp[i * 16 + q * 4 + r];   // {c0, c1}
                    v = __expf(fmaf(acc[i][0][r], cc.y, cc.x))
                      + __expf(fmaf(acc[i][1][r], cc.y, cc.x))
                      + __expf(fmaf(acc[i][2][r], cc.y, cc.x))
                      + __expf(fmaf(acc[i][3][r], cc.y, cc.x));  // args <= ~0
                    #pragma unroll
                    for (int o = 1; o < 16; o <<= 1) v += __shfl_xor(v, o);
                }
                if (l15 == 0) dst[i * 16 + q * 4 + r] = v;
            }
    }
}

// ---------------------------------------------------------------------------
// Reduce 64 max partials -> affine exp coefficients {c0,c1} per row
//   d = 1 - maxdot; t = 1/(HP*(d+eps)); arg(dot) = dot*t + (d-1)*t
__global__ void k_dmin(const float* __restrict__ pmax, float* __restrict__ ctv)
{
    int i = blockIdx.x * 256 + threadIdx.x;   // 0 .. B*N-1
    float g = -1e30f;
    #pragma unroll
    for (int z = 0; z < 64; ++z) g = fmaxf(g, pmax[(size_t)z * BN + i]);
    float d = 1.f - g;
    float t = 1.f / (HP * (d + EPSM));
    ((float2*)ctv)[i] = (float2){(d - 1.f) * t, t};
}

// ---------------------------------------------------------------------------
// Stage 1 of final reduction: per-row 1/s, block-sum, atomicAdd per batch.
__global__ void k_partial(const float* __restrict__ ssp, float* __restrict__ acc)
{
    int i = blockIdx.x * 256 + threadIdx.x;   // 0 .. B*N-1 (block spans one batch)
    float t = 0.f;
    #pragma unroll
    for (int z = 0; z < 64; ++z) t += ssp[(size_t)z * BN + i];
    float s = 1.f / t;
    #pragma unroll
    for (int o = 32; o > 0; o >>= 1) s += __shfl_xor(s, o);
    __shared__ float red[4];
    if ((threadIdx.x & 63) == 0) red[threadIdx.x >> 6] = s;
    __syncthreads();
    if (threadIdx.x == 0)
        atomicAdd(&acc[i >> 12], red[0] + red[1] + red[2] + red[3]);
}

__global__ void k_out(const float* __restrict__ acc, float* __restrict__ out)
{
    int b = threadIdx.x;
    if (b < Bb) out[b] = -logf(acc[b] * (1.f / Nn));
}

// ---------------------------------------------------------------------------
extern "C" void kernel_launch(void* const* d_in, const int* in_sizes, int n_in,
                              void* d_out, int out_size, void* d_ws, size_t ws_size,
                              hipStream_t stream)
{
    const float* fx = (const float*)d_in[0];
    const float* fy = (const float*)d_in[1];
    float* out = (float*)d_out;
    float* ws  = (float*)d_ws;

    float* mean = ws + OFF_MEAN;
    float* acc  = ws + OFF_ACC;
    float* ctv  = ws + OFF_CTV;
    float* pmax = ws + OFF_PMAX;
    float* ssp  = ws + OFF_SSP;       // aliases pmax (pmax dead after k_dmin)
    ushort* fxn = (ushort*)(ws + OFF_FXN);
    ushort* fyn = (ushort*)(ws + OFF_FYN);

    // zero the atomicAdd accumulators (mean @0..511, acc @512..515)
    hipMemsetAsync(ws, 0, 516 * sizeof(float), stream);

    k_mean<<<dim3(Bb * 32), dim3(128), 0, stream>>>(fy, mean);
    k_norm<<<dim3(BN / 16), dim3(256), 0, stream>>>(fx, fy, mean, fxn, fyn);

    dim3 gg(32, 8, Bb);   // 1024 blocks, 4 m-tiles each, barrier-free
    k_gemm<1><<<gg, dim3(256), 0, stream>>>(fxn, fyn, pmax, nullptr, nullptr);
    k_dmin<<<dim3(BN / 256), dim3(256), 0, stream>>>(pmax, ctv);
    k_gemm<2><<<gg, dim3(256), 0, stream>>>(fxn, fyn, nullptr, ctv, ssp);
    k_partial<<<dim3(BN / 256), dim3(256), 0, stream>>>(ssp, acc);
    k_out<<<dim3(1), dim3(64), 0, stream>>>(acc, out);
}